// Round 1
// baseline (451.161 us; speedup 1.0000x reference)
//
#include <hip/hip_runtime.h>
#include <hip/hip_bf16.h>

#define NN 8192
#define KK 32

__device__ __forceinline__ float wave_reduce_sum(float v) {
    #pragma unroll
    for (int off = 32; off > 0; off >>= 1) v += __shfl_down(v, off);
    return v;
}
__device__ __forceinline__ float wave_reduce_max(float v) {
    #pragma unroll
    for (int off = 32; off > 0; off >>= 1) v = fmaxf(v, __shfl_down(v, off));
    return v;
}

// ---------- K0: column softmax stats of C (N x K), one block per column l ----------
__global__ void kc_colstats(const float* __restrict__ C, float* __restrict__ mC,
                            float* __restrict__ sC) {
    const int l = blockIdx.x;
    const int t = threadIdx.x;  // 256
    __shared__ float wmax[4], wsum[4];

    float m = -INFINITY;
    for (int u = 0; u < NN / 256; ++u)
        m = fmaxf(m, C[(size_t)(u * 256 + t) * KK + l]);
    m = wave_reduce_max(m);
    if ((t & 63) == 0) wmax[t >> 6] = m;
    __syncthreads();
    const float mm = fmaxf(fmaxf(wmax[0], wmax[1]), fmaxf(wmax[2], wmax[3]));

    float s = 0.f;
    for (int u = 0; u < NN / 256; ++u)
        s += __expf(C[(size_t)(u * 256 + t) * KK + l] - mm);
    s = wave_reduce_sum(s);
    if ((t & 63) == 0) wsum[t >> 6] = s;
    __syncthreads();
    if (t == 0) {
        mC[l] = mm;
        sC[l] = wsum[0] + wsum[1] + wsum[2] + wsum[3];
    }
}

// ---------- K1: column softmax of X (K x N) -> Xs, one thread per column n ----------
__global__ void kx_softmax(const float* __restrict__ X, float* __restrict__ Xs) {
    const int n = blockIdx.x * 256 + threadIdx.x;
    float e[KK];
    float m = -INFINITY;
    #pragma unroll
    for (int k = 0; k < KK; ++k) {
        e[k] = X[(size_t)k * NN + n];
        m = fmaxf(m, e[k]);
    }
    float s = 0.f;
    #pragma unroll
    for (int k = 0; k < KK; ++k) {
        e[k] = __expf(e[k] - m);
        s += e[k];
    }
    const float r = 1.f / s;
    #pragma unroll
    for (int k = 0; k < KK; ++k) Xs[(size_t)k * NN + n] = e[k] * r;
}

// ---------- K2: E = Xs @ Cs  (K x K), reduced over n with LDS staging ----------
__global__ void ke_E(const float* __restrict__ Xs, const float* __restrict__ C,
                     const float* __restrict__ mC, const float* __restrict__ sC,
                     float* __restrict__ E) {
    __shared__ float xsl[KK * 33];   // [k][n], stride 33 (conflict-free)
    __shared__ float cql[32 * 33];   // [n][l], stride 33
    __shared__ float mCl[KK], rsCl[KK];
    const int tid = threadIdx.x;     // 1024
    if (tid < KK) { mCl[tid] = mC[tid]; rsCl[tid] = 1.f / sC[tid]; }
    const int k = tid & 31, l = tid >> 5;
    const int sk = tid >> 5, sn = tid & 31;
    const int nb0 = blockIdx.x * (NN / 64);  // 128 n per block
    float acc = 0.f;
    for (int b = 0; b < 4; ++b) {
        const int nb = nb0 + b * 32;
        __syncthreads();
        xsl[sk * 33 + sn] = Xs[(size_t)sk * NN + nb + sn];           // coalesced
        const float cv = C[(size_t)nb * KK + tid];                   // coalesced
        cql[(tid >> 5) * 33 + (tid & 31)] =
            __expf(cv - mCl[tid & 31]) * rsCl[tid & 31];
        __syncthreads();
        #pragma unroll
        for (int n = 0; n < 32; ++n)
            acc = fmaf(xsl[k * 33 + n], cql[n * 33 + l], acc);
    }
    atomicAdd(&E[k * KK + l], acc);
}

// ---------- K3: M = E^T E (symmetric) ----------
__global__ void km_M(const float* __restrict__ E, float* __restrict__ M) {
    __shared__ float el[KK * 33];  // [k][l] stride 33
    const int tid = threadIdx.x;   // 1024
    el[(tid >> 5) * 33 + (tid & 31)] = E[tid];
    __syncthreads();
    const int l1 = tid & 31, l2 = tid >> 5;
    float acc = 0.f;
    #pragma unroll
    for (int kk = 0; kk < KK; ++kk)
        acc = fmaf(el[kk * 33 + l1], el[kk * 33 + l2], acc);
    M[tid] = acc;  // M[l2][l1], symmetric => correct
}

// ---------- K4: per-node prep: Xt, Wt = 2a*M*x, f = beta - a*q ----------
__global__ void kp_prep(const float* __restrict__ X, const float* __restrict__ beta,
                        const float* __restrict__ a_ptr, const float* __restrict__ M,
                        float* __restrict__ Xt, float* __restrict__ Wt,
                        float* __restrict__ f) {
    __shared__ float Ml[KK * KK];
    const int tid = threadIdx.x;  // 256
    #pragma unroll
    for (int u = 0; u < 4; ++u) Ml[tid + 256 * u] = M[tid + 256 * u];
    __syncthreads();
    const int n = blockIdx.x * 256 + tid;
    float x[KK], v[KK];
    #pragma unroll
    for (int k = 0; k < KK; ++k) x[k] = X[(size_t)k * NN + n];
    const float a = a_ptr[0];
    #pragma unroll
    for (int l = 0; l < KK; ++l) {
        float s = 0.f;
        #pragma unroll
        for (int k = 0; k < KK; ++k) s = fmaf(Ml[l * KK + k], x[k], s);
        v[l] = s;
    }
    float q = 0.f;
    #pragma unroll
    for (int l = 0; l < KK; ++l) q = fmaf(x[l], v[l], q);
    f[n] = beta[n] - a * q;
    const float two_a = 2.f * a;
    #pragma unroll
    for (int k = 0; k < KK; ++k) {
        Xt[(size_t)n * KK + k] = x[k];
        Wt[(size_t)n * KK + k] = two_a * v[k];
    }
}

// ---------- K5: the big fused pair kernel ----------
#define II 32
#define JPANEL 1024

__global__ __launch_bounds__(256) void kl_main(
    const float* __restrict__ A, const float* __restrict__ Xt,
    const float* __restrict__ Wt, const float* __restrict__ f,
    double* __restrict__ acc) {
    const int tid = threadIdx.x;
    const int ibase = blockIdx.y * II;
    const int jpan = blockIdx.x * JPANEL;

    float accA = 0.f, accS = 0.f;

    for (int c = 0; c < JPANEL / 256; ++c) {
        const int jj = jpan + c * 256 + tid;
        const float4* w4 = (const float4*)&Wt[(size_t)jj * KK];
        const float4 w0 = w4[0], w1 = w4[1], w2 = w4[2], w3 = w4[3];
        const float4 w4r = w4[4], w5 = w4[5], w6 = w4[6], w7 = w4[7];
        const float fj = f[jj];

        #pragma unroll 4
        for (int i = 0; i < II; ++i) {
            const int irow = ibase + i;
            const float Av = A[(size_t)irow * NN + jj];     // coalesced
            const float4* x4 = (const float4*)&Xt[(size_t)irow * KK];  // uniform
            const float4 x0 = x4[0], x1 = x4[1], x2 = x4[2], x3 = x4[3];
            const float4 x4r = x4[4], x5 = x4[5], x6 = x4[6], x7 = x4[7];

            float t0 = x0.x * w0.x, t1 = x0.y * w0.y, t2 = x0.z * w0.z, t3 = x0.w * w0.w;
            t0 = fmaf(x1.x, w1.x, t0); t1 = fmaf(x1.y, w1.y, t1);
            t2 = fmaf(x1.z, w1.z, t2); t3 = fmaf(x1.w, w1.w, t3);
            t0 = fmaf(x2.x, w2.x, t0); t1 = fmaf(x2.y, w2.y, t1);
            t2 = fmaf(x2.z, w2.z, t2); t3 = fmaf(x2.w, w2.w, t3);
            t0 = fmaf(x3.x, w3.x, t0); t1 = fmaf(x3.y, w3.y, t1);
            t2 = fmaf(x3.z, w3.z, t2); t3 = fmaf(x3.w, w3.w, t3);
            t0 = fmaf(x4r.x, w4r.x, t0); t1 = fmaf(x4r.y, w4r.y, t1);
            t2 = fmaf(x4r.z, w4r.z, t2); t3 = fmaf(x4r.w, w4r.w, t3);
            t0 = fmaf(x5.x, w5.x, t0); t1 = fmaf(x5.y, w5.y, t1);
            t2 = fmaf(x5.z, w5.z, t2); t3 = fmaf(x5.w, w5.w, t3);
            t0 = fmaf(x6.x, w6.x, t0); t1 = fmaf(x6.y, w6.y, t1);
            t2 = fmaf(x6.z, w6.z, t2); t3 = fmaf(x6.w, w6.w, t3);
            t0 = fmaf(x7.x, w7.x, t0); t1 = fmaf(x7.y, w7.y, t1);
            t2 = fmaf(x7.z, w7.z, t2); t3 = fmaf(x7.w, w7.w, t3);

            const float th = f[irow] + fj + ((t0 + t1) + (t2 + t3));
            accA = fmaf(th, Av, accA);
            const float sp = fmaxf(th, 0.f) + __logf(1.f + __expf(-fabsf(th)));
            accS += (irow != jj) ? sp : 0.f;
        }
    }

    accA = wave_reduce_sum(accA);
    accS = wave_reduce_sum(accS);
    __shared__ float rA[4], rS[4];
    if ((tid & 63) == 0) { rA[tid >> 6] = accA; rS[tid >> 6] = accS; }
    __syncthreads();
    if (tid == 0) {
        const double dA = (double)rA[0] + rA[1] + rA[2] + rA[3];
        const double dS = (double)rS[0] + rS[1] + rS[2] + rS[3];
        atomicAdd(&acc[0], dA);
        atomicAdd(&acc[1], dS);
    }
}

// ---------- K6: finalize ----------
__global__ void kf_final(const double* __restrict__ acc, float* __restrict__ out) {
    out[0] = (float)(0.5 * (acc[0] - acc[1]));
}

extern "C" void kernel_launch(void* const* d_in, const int* in_sizes, int n_in,
                              void* d_out, int out_size, void* d_ws, size_t ws_size,
                              hipStream_t stream) {
    const float* Ain    = (const float*)d_in[0];  // (N, N)
    const float* betain = (const float*)d_in[1];  // (N,)
    const float* ain    = (const float*)d_in[2];  // (1,)
    const float* Xin    = (const float*)d_in[3];  // (K, N)
    const float* Cin    = (const float*)d_in[4];  // (N, K)
    float* out = (float*)d_out;

    char* ws = (char*)d_ws;
    float*  E   = (float*)(ws + 0);            // 4096 B
    double* acc = (double*)(ws + 4096);        // 16 B
    float*  mC  = (float*)(ws + 4160);         // 128 B
    float*  sC  = (float*)(ws + 4288);         // 128 B
    float*  M   = (float*)(ws + 4608);         // 4096 B
    float*  f   = (float*)(ws + 8704);         // 32768 B
    float*  Xs  = (float*)(ws + 65536);        // 1 MB
    float*  Xt  = (float*)(ws + 65536 + 1048576);
    float*  Wt  = (float*)(ws + 65536 + 2097152);
    // total: 65536 + 3*1048576 = 3,211,264 bytes

    hipMemsetAsync(ws, 0, 4112, stream);  // zero E accumulator + double acc

    kc_colstats<<<KK, 256, 0, stream>>>(Cin, mC, sC);
    kx_softmax<<<NN / 256, 256, 0, stream>>>(Xin, Xs);
    ke_E<<<64, 1024, 0, stream>>>(Xs, Cin, mC, sC, E);
    km_M<<<1, 1024, 0, stream>>>(E, M);
    kp_prep<<<NN / 256, 256, 0, stream>>>(Xin, betain, ain, M, Xt, Wt, f);
    kl_main<<<dim3(NN / JPANEL, NN / II), 256, 0, stream>>>(Ain, Xt, Wt, f, acc);
    kf_final<<<1, 1, 0, stream>>>(acc, out);
}